// Round 1
// baseline (7552.208 us; speedup 1.0000x reference)
//
#include <hip/hip_runtime.h>
#include <math.h>

// Model dims
#define BB     32
#define DD     768
#define DIi    1536
#define DCONVi 1792
#define NHi    8
#define HDi    192
#define DSi    128
#define NCi    100
#define RIN    3336   // 2*DI + 2*DS + NH
#define NLAYER 12
#define GRID   512    // 2 blocks/CU on 256 CUs -> guaranteed co-resident with
                      // __launch_bounds__(256,2) and 36.9 KB LDS/block

struct P {
  const float *x, *hf, *pw, *pb, *cw4, *cb4, *bg, *bnb, *brm, *brv, *cst, *pos;
  const float *ipw, *cw, *cb1, *alog, *dtb, *dpar, *nw, *opw, *mcs, *ssm;
  const float *fg, *fb, *fcw, *fcb;
  const int* pidx;
  float *out, *cin0, *cin1, *cin2, *cin3, *part, *t0, *t1, *zx, *yb, *sq, *dp;
  unsigned* barr;  // [GRID] per-block flags + [1] go word, zeroed per launch
};

static __device__ __forceinline__ float siluf(float x) { return x / (1.0f + expf(-x)); }

// ---------------------------------------------------------------------------
// Device-wide barrier (monotonic phase, no reset needed within a launch).
// Arrival: one agent-scope release store per block (no shared counter
// contention). Block 0 polls all flags (256 threads x 2 each), then releases
// the go word; everyone else acquires go. Release/acquire at AGENT scope
// handles cross-XCD L2 writeback/invalidate.
// ---------------------------------------------------------------------------
static __device__ __forceinline__ void gridbar(unsigned* flags, unsigned* go, unsigned ph,
                                               int bid, int tid) {
  __syncthreads();
  if (bid == 0) {
    if (tid == 0)
      __hip_atomic_store(&flags[0], ph, __ATOMIC_RELEASE, __HIP_MEMORY_SCOPE_AGENT);
#pragma unroll
    for (int j = 0; j < GRID / 256; j++) {
      int i = tid + j * 256;
      while (__hip_atomic_load(&flags[i], __ATOMIC_ACQUIRE, __HIP_MEMORY_SCOPE_AGENT) < ph)
        __builtin_amdgcn_s_sleep(1);
    }
    __syncthreads();
    if (tid == 0)
      __hip_atomic_store(go, ph, __ATOMIC_RELEASE, __HIP_MEMORY_SCOPE_AGENT);
  } else {
    if (tid == 0) {
      __hip_atomic_store(&flags[bid], ph, __ATOMIC_RELEASE, __HIP_MEMORY_SCOPE_AGENT);
      while (__hip_atomic_load(go, __ATOMIC_ACQUIRE, __HIP_MEMORY_SCOPE_AGENT) < ph)
        __builtin_amdgcn_s_sleep(2);
    }
    __syncthreads();
  }
}

// ---------------------------------------------------------------------------
// Stage: patch embed + assemble conv0 input (B,D,10) = [cnn_state[0] | h]
// ---------------------------------------------------------------------------
static __device__ void st_patch(const P& p, int bid, int tid) {
  for (int idx = bid * 256 + tid; idx < BB * DD * 10; idx += GRID * 256) {
    int l = idx % 10;
    int d = (idx / 10) % DD;
    int b = idx / (10 * DD);
    float v;
    if (l < 4) {
      v = p.cst[(b * DD + d) * 4 + l];
    } else {
      int w = l - 4;
      float acc = p.pb[d];
#pragma unroll
      for (int q = 0; q < 16; q++) acc += p.x[b * 96 + q * 6 + w] * p.pw[d * 16 + q];
      v = acc;
    }
    p.cin0[idx] = v;
  }
}

// ---------------------------------------------------------------------------
// Stage: conv as split-K GEMM. 768 tiles (48 m-tiles x 16 k-splits), one tile
// per 128-thread half. part layout [16][768][B*LOUT].
// ---------------------------------------------------------------------------
template <int LIN, int LOUT>
static __device__ void st_conv(const float* __restrict__ cin, const float* __restrict__ w,
                               float* __restrict__ part, int bid, int tid, char* smem) {
  const int NN = BB * LOUT;
  typedef float WlT[16][8][5];
  typedef float IlT[8][BB][LIN];
  WlT* Wl = (WlT*)smem;                       // [2]
  IlT* Il = (IlT*)(smem + 2 * sizeof(WlT));   // [2]
  int half = tid >> 7, lt = tid & 127;
  int t = bid * 2 + half;
  if (t >= 768) return;  // uniform per block (bid >= 384)
  int bx = t >> 4, by = t & 15;
  int m0 = bx * 16, di0 = by * 48;
  int tm = lt >> 4, tb = lt & 15;
  float acc[2][2][LOUT] = {};

  for (int cc = 0; cc < 6; cc++) {
    int dib = di0 + cc * 8;
    {  // stage weights: 16m x 8di x 5k
      int m = lt >> 3, di = lt & 7;
      const float* wp = w + (size_t)(m0 + m) * (DD * 5) + (dib + di) * 5;
#pragma unroll
      for (int k = 0; k < 5; k++) Wl[half][m][di][k] = wp[k];
    }
#pragma unroll
    for (int j = 0; j < 2; j++) {  // stage input: 8di x 32b x LIN
      int flat = lt + 128 * j;
      int di = flat >> 5, b = flat & 31;
      const float* ip = cin + (size_t)(b * DD + dib + di) * LIN;
#pragma unroll
      for (int l = 0; l < LIN; l++) Il[half][di][b][l] = ip[l];
    }
    __syncthreads();
#pragma unroll
    for (int di = 0; di < 8; di++) {
      float a0[LIN], a1[LIN];
#pragma unroll
      for (int l = 0; l < LIN; l++) {
        a0[l] = Il[half][di][2 * tb][l];
        a1[l] = Il[half][di][2 * tb + 1][l];
      }
      float w0[5], w1[5];
#pragma unroll
      for (int k = 0; k < 5; k++) {
        w0[k] = Wl[half][2 * tm][di][k];
        w1[k] = Wl[half][2 * tm + 1][di][k];
      }
#pragma unroll
      for (int l = 0; l < LOUT; l++)
#pragma unroll
        for (int k = 0; k < 5; k++) {
          acc[0][0][l] += w0[k] * a0[l + k];
          acc[0][1][l] += w0[k] * a1[l + k];
          acc[1][0][l] += w1[k] * a0[l + k];
          acc[1][1][l] += w1[k] * a1[l + k];
        }
    }
    __syncthreads();
  }
#pragma unroll
  for (int mm = 0; mm < 2; mm++)
#pragma unroll
    for (int bb2 = 0; bb2 < 2; bb2++)
#pragma unroll
      for (int l = 0; l < LOUT; l++) {
        int d_ = m0 + 2 * tm + mm;
        int n = (2 * tb + bb2) * LOUT + l;
        part[((size_t)by * DD + d_) * NN + n] = acc[mm][bb2][l];
      }
}

// ---------------------------------------------------------------------------
// Stage: sum partials + bias + BN + relu + pool; write next conv input (with
// state prefix) or final tok (+pos_embed). 96 blocks active.
// ---------------------------------------------------------------------------
template <int LOUT, int PF, int MODE, int LINn>
static __device__ void st_bnrelu(const float* __restrict__ part, const float* __restrict__ cb,
                                 const float* __restrict__ bg, const float* __restrict__ bbeta,
                                 const float* __restrict__ rm, const float* __restrict__ rv,
                                 float* __restrict__ outp, const float* __restrict__ stn,
                                 const float* __restrict__ pos, const int* __restrict__ pidx,
                                 int bid, int tid) {
  int idx = bid * 256 + tid;
  if (idx >= BB * DD) return;
  int d = idx % DD, b = idx / DD;
  const int NN = BB * LOUT;
  float inv = rsqrtf(rv[d] + 1e-5f);
  float v[LOUT];
#pragma unroll
  for (int l = 0; l < LOUT; l++) {
    float s = cb[d];
#pragma unroll
    for (int ss = 0; ss < 16; ss++) s += part[((size_t)ss * DD + d) * NN + b * LOUT + l];
    s = (s - rm[d]) * inv * bg[d] + bbeta[d];
    v[l] = fmaxf(s, 0.0f);
  }
  constexpr int LP = LOUT / PF;
  float pm[LP];
#pragma unroll
  for (int lp = 0; lp < LP; lp++) {
    float m = v[lp * PF];
#pragma unroll
    for (int j = 1; j < PF; j++) m = fmaxf(m, v[lp * PF + j]);
    pm[lp] = m;
  }
  if constexpr (MODE == 0) {
    float* o = outp + (size_t)(b * DD + d) * LINn;
#pragma unroll
    for (int j = 0; j < 4; j++) o[j] = stn[(b * DD + d) * 4 + j];
#pragma unroll
    for (int lp = 0; lp < LP; lp++) o[4 + lp] = pm[lp];
  } else {
    int clip = (*pidx < 299) ? *pidx : 299;
    outp[b * DD + d] = pm[0] + pos[(1 + clip) * DD + d];
  }
}

// ---------------------------------------------------------------------------
// Stage: in_proj GEMM, split-K=4. 420 tiles (105 m-tiles x 4), one per half.
// Tile 0 also zeroes sq for this layer's SSM atomics. Diagonal tiles
// materialize the residual-updated tok into tokwr.
// ---------------------------------------------------------------------------
static __device__ void st_inproj(const float* __restrict__ W, const float* __restrict__ tokrd,
                                 const float* __restrict__ dp, int use_dp,
                                 float* __restrict__ tokwr, float* __restrict__ zx,
                                 float* __restrict__ sq, int bid, int tid, char* smem) {
  typedef float M36[64][36];
  M36* Wl = (M36*)smem;                      // [2] -> 18432 B
  M36* Tl = (M36*)(smem + 2 * sizeof(M36));  // [2] -> +18432 = 36864 B
  int half = tid >> 7, lt = tid & 127;
  int t = bid * 2 + half;
  if (t >= 420) return;  // uniform per block (bid >= 210)
  if (t == 0 && lt < BB) sq[lt] = 0.0f;
  int bx = t >> 2, by = t & 3;
  int m0 = bx * 32;
  int tm = lt & 15, tb = lt >> 4;
  float acc[2][4] = {};
  for (int c = 0; c < 3; c++) {
    int k0 = by * 192 + c * 64;
#pragma unroll
    for (int j = 0; j < 4; j++) {  // stage W (transposed)
      int flat = lt + 128 * j;
      int m = flat >> 4, kf = flat & 15;
      float4 w4 = {0.f, 0.f, 0.f, 0.f};
      if (m0 + m < RIN) w4 = *(const float4*)(W + (size_t)(m0 + m) * DD + k0 + kf * 4);
      Wl[half][kf * 4 + 0][m] = w4.x;
      Wl[half][kf * 4 + 1][m] = w4.y;
      Wl[half][kf * 4 + 2][m] = w4.z;
      Wl[half][kf * 4 + 3][m] = w4.w;
    }
#pragma unroll
    for (int j = 0; j < 4; j++) {  // stage tok (+ lazy residual partials)
      int flat = lt + 128 * j;
      int b = flat >> 4, kf = flat & 15;
      int off = b * DD + k0 + kf * 4;
      float4 t4 = *(const float4*)(tokrd + off);
      if (use_dp) {
#pragma unroll
        for (int s = 0; s < 4; s++) {
          float4 d4 = *(const float4*)(dp + (size_t)s * (BB * DD) + off);
          t4.x += d4.x; t4.y += d4.y; t4.z += d4.z; t4.w += d4.w;
        }
        if (bx == by) *(float4*)(tokwr + off) = t4;
      }
      Tl[half][kf * 4 + 0][b] = t4.x;
      Tl[half][kf * 4 + 1][b] = t4.y;
      Tl[half][kf * 4 + 2][b] = t4.z;
      Tl[half][kf * 4 + 3][b] = t4.w;
    }
    __syncthreads();
#pragma unroll 4
    for (int kk = 0; kk < 64; kk++) {
      float2 wv = *(const float2*)&Wl[half][kk][2 * tm];
      float4 tv = *(const float4*)&Tl[half][kk][4 * tb];
      acc[0][0] += wv.x * tv.x; acc[0][1] += wv.x * tv.y;
      acc[0][2] += wv.x * tv.z; acc[0][3] += wv.x * tv.w;
      acc[1][0] += wv.y * tv.x; acc[1][1] += wv.y * tv.y;
      acc[1][2] += wv.y * tv.z; acc[1][3] += wv.y * tv.w;
    }
    __syncthreads();
  }
#pragma unroll
  for (int mm = 0; mm < 2; mm++)
#pragma unroll
    for (int b2 = 0; b2 < 4; b2++) {
      int r = m0 + 2 * tm + mm;
      if (r < RIN) zx[((size_t)by * BB + 4 * tb + b2) * RIN + r] = acc[mm][b2];
    }
}

// ---------------------------------------------------------------------------
// Stage: SSM. 768 units = b(32) x h(8) x pchunk(3 of 64); unit u = block
// (+GRID for second round). Same math as the proven k_ssm.
// ---------------------------------------------------------------------------
static __device__ void ssm_unit(const P& p, const float* __restrict__ ssmL,
                                const float* __restrict__ cstL, const float* __restrict__ cwL,
                                const float* __restrict__ cbL, const float* __restrict__ alogL,
                                const float* __restrict__ dtbL, const float* __restrict__ dparL,
                                int u, int tid, char* smem) {
  struct SS {
    float Cl[DSi], Bl[DSi], pl[DSi], xhl[64], zsl[64];
    float s_dt, s_dA, s_coef, sqw[4];
  };
  SS& S = *(SS*)smem;
  const float* zx = p.zx;
  int b = u / 24;
  int rem = u % 24;
  int h = rem / 3;
  int pc = rem % 3;
  int p0 = pc * 64;
  __syncthreads();  // guard LDS reuse across units/stages

  auto convgate = [&](int c) -> float {
    float zr = 0.f;
#pragma unroll
    for (int s = 0; s < 4; s++) zr += zx[(size_t)s * (BB * RIN) + b * RIN + (DIi + c)];
    const float* cs = cstL + (size_t)(b * DCONVi + c) * 4;
    const float* wc = cwL + (size_t)c * 4;
    float v = cs[1] * wc[0] + cs[2] * wc[1] + cs[3] * wc[2] + zr * wc[3] + cbL[c];
    return siluf(v);
  };

  if (tid < 128) S.Cl[tid] = convgate(DIi + DSi + tid);
  else S.Bl[tid - 128] = convgate(DIi + (tid - 128));
  __syncthreads();
  if (tid < 128) {
    S.pl[tid] = S.Bl[tid] * S.Cl[tid];
  } else if (tid < 192) {
    int q = tid - 128;
    S.xhl[q] = convgate(h * HDi + p0 + q);
  } else {
    int q = tid - 192;
    float zr = 0.f;
#pragma unroll
    for (int s = 0; s < 4; s++)
      zr += zx[(size_t)s * (BB * RIN) + b * RIN + (h * HDi + p0 + q)];
    S.zsl[q] = siluf(zr);
  }
  if (tid == 0) {
    float zr = 0.f;
#pragma unroll
    for (int s = 0; s < 4; s++)
      zr += zx[(size_t)s * (BB * RIN) + b * RIN + (DIi + DCONVi + h)];
    float xdt = zr + dtbL[h];
    float dt = fmaxf(xdt, 0.f) + log1pf(expf(-fabsf(xdt)));  // stable softplus
    S.s_dt = dt;
    S.s_dA = expf(-expf(alogL[h]) * dt);
  }
  __syncthreads();
  if (tid < 64) {
    float v = S.pl[tid] + S.pl[tid + 64];
#pragma unroll
    for (int m = 1; m < 64; m <<= 1) v += __shfl_xor(v, m, 64);
    if (tid == 0) S.s_coef = S.s_dt * v + dparL[h];
  }
  __syncthreads();

  float dA = S.s_dA, coef = S.s_coef;
  int wv = tid >> 6, lane = tid & 63;
  float c0 = S.Cl[2 * lane], c1 = S.Cl[2 * lane + 1];
  float gsq = 0.f;
  const float* sb = ssmL + (size_t)((b * NHi + h) * HDi) * DSi;
  for (int i = 0; i < 16; i++) {
    int pp = p0 + wv * 16 + i;
    float2 v2 = *(const float2*)(sb + (size_t)pp * DSi + 2 * lane);
    float s = v2.x * c0 + v2.y * c1;
#pragma unroll
    for (int m = 1; m < 64; m <<= 1) s += __shfl_xor(s, m, 64);
    if (lane == 0) {
      float yv = dA * s + coef * S.xhl[pp - p0];
      p.yb[b * DIi + h * HDi + pp] = yv;
      float g = yv * S.zsl[pp - p0];
      gsq += g * g;
    }
  }
  if (lane == 0) S.sqw[wv] = gsq;
  __syncthreads();
  if (tid == 0) atomicAdd(&p.sq[b], S.sqw[0] + S.sqw[1] + S.sqw[2] + S.sqw[3]);
}

static __device__ void st_ssm(const P& p, int L, int bid, int tid, char* smem) {
  const float* ssmL = p.ssm + (size_t)L * BB * NHi * HDi * DSi;
  const float* cstL = p.mcs + (size_t)L * BB * DCONVi * 4;
  const float* cwL = p.cw + (size_t)L * DCONVi * 4;
  const float* cbL = p.cb1 + (size_t)L * DCONVi;
  const float* alogL = p.alog + L * NHi;
  const float* dtbL = p.dtb + L * NHi;
  const float* dparL = p.dpar + L * NHi;
  ssm_unit(p, ssmL, cstL, cwL, cbL, alogL, dtbL, dparL, bid, tid, smem);
  if (bid < 768 - GRID)
    ssm_unit(p, ssmL, cstL, cwL, cbL, alogL, dtbL, dparL, bid + GRID, tid, smem);
}

// ---------------------------------------------------------------------------
// Stage: out_proj GEMM with fused gate+RMSnorm on staging. 192 tiles
// (48 m-tiles x 4 k-splits), one per half. Writes dp partials [4][32][768].
// ---------------------------------------------------------------------------
static __device__ void st_outproj(const float* __restrict__ W, const float* __restrict__ y,
                                  const float* __restrict__ zx, const float* __restrict__ sq,
                                  const float* __restrict__ nw, float* __restrict__ dp,
                                  int bid, int tid, char* smem) {
  struct OS {
    float Wl[64][20];
    float Gl[64][36];
    float sl[BB];
  };
  OS* Sa = (OS*)smem;  // [2] -> 28928 B
  int half = tid >> 7, lt = tid & 127;
  int t = bid * 2 + half;
  if (t >= 192) return;  // uniform per block (bid >= 96)
  OS& S = Sa[half];
  if (lt < BB) S.sl[lt] = rsqrtf(sq[lt] * (1.0f / (float)DIi) + 1e-5f);
  __syncthreads();
  int bx = t >> 2, by = t & 3;
  int m0 = bx * 16;
  int tm = lt & 7, tb = lt >> 3;
  float acc[2][2] = {};
  for (int c = 0; c < 6; c++) {
    int k0 = by * 384 + c * 64;
#pragma unroll
    for (int j = 0; j < 2; j++) {  // stage W
      int flat = lt + 128 * j;
      int m = flat >> 4, kf = flat & 15;
      float4 w4 = *(const float4*)(W + (size_t)(m0 + m) * DIi + k0 + kf * 4);
      S.Wl[kf * 4 + 0][m] = w4.x;
      S.Wl[kf * 4 + 1][m] = w4.y;
      S.Wl[kf * 4 + 2][m] = w4.z;
      S.Wl[kf * 4 + 3][m] = w4.w;
    }
#pragma unroll
    for (int j = 0; j < 4; j++) {  // stage g = y*silu(z)*scale*norm_w
      int flat = lt + 128 * j;
      int b = flat >> 4, kf = flat & 15;
      int k = k0 + kf * 4;
      float4 y4 = *(const float4*)(y + b * DIi + k);
      float4 z4 = {0.f, 0.f, 0.f, 0.f};
#pragma unroll
      for (int s = 0; s < 4; s++) {
        float4 tz = *(const float4*)(zx + (size_t)s * (BB * RIN) + b * RIN + k);
        z4.x += tz.x; z4.y += tz.y; z4.z += tz.z; z4.w += tz.w;
      }
      float4 n4 = *(const float4*)(nw + k);
      float sc = S.sl[b];
      S.Gl[kf * 4 + 0][b] = y4.x * siluf(z4.x) * sc * n4.x;
      S.Gl[kf * 4 + 1][b] = y4.y * siluf(z4.y) * sc * n4.y;
      S.Gl[kf * 4 + 2][b] = y4.z * siluf(z4.z) * sc * n4.z;
      S.Gl[kf * 4 + 3][b] = y4.w * siluf(z4.w) * sc * n4.w;
    }
    __syncthreads();
#pragma unroll 4
    for (int kk = 0; kk < 64; kk++) {
      float2 w2 = *(const float2*)&S.Wl[kk][2 * tm];
      float2 g2 = *(const float2*)&S.Gl[kk][2 * tb];
      acc[0][0] += w2.x * g2.x; acc[0][1] += w2.x * g2.y;
      acc[1][0] += w2.y * g2.x; acc[1][1] += w2.y * g2.y;
    }
    __syncthreads();
  }
#pragma unroll
  for (int mm = 0; mm < 2; mm++)
#pragma unroll
    for (int b2 = 0; b2 < 2; b2++)
      dp[((size_t)by * BB + 2 * tb + b2) * DD + m0 + 2 * tm + mm] = acc[mm][b2];
}

// ---------------------------------------------------------------------------
// Stage: final layernorm + history update + logits. Blocks 0..31 (one batch
// each). out = [logits (32x100) | history (32x768)]
// ---------------------------------------------------------------------------
static __device__ void st_final(const float* __restrict__ tok, const float* __restrict__ dp,
                                const float* __restrict__ hf, const float* __restrict__ fg,
                                const float* __restrict__ fb, const float* __restrict__ fcw,
                                const float* __restrict__ fcb, const int* __restrict__ pidx,
                                float* __restrict__ out, int bid, int tid, char* smem) {
  if (bid >= BB) return;
  struct FS {
    float tl[DD], hl[DD], red1[4], red2[4];
  };
  FS& S = *(FS*)smem;
  int b = bid;
  int wv = tid >> 6, lane = tid & 63;
  float psum = 0.f;
  for (int d = tid; d < DD; d += 256) {
    float v = tok[b * DD + d];
#pragma unroll
    for (int s = 0; s < 4; s++) v += dp[(size_t)s * (BB * DD) + b * DD + d];
    S.tl[d] = v;
    psum += v;
  }
#pragma unroll
  for (int m = 1; m < 64; m <<= 1) psum += __shfl_xor(psum, m, 64);
  if (lane == 0) S.red1[wv] = psum;
  __syncthreads();
  float mu = (S.red1[0] + S.red1[1] + S.red1[2] + S.red1[3]) * (1.0f / (float)DD);
  float vsum = 0.f;
  for (int d = tid; d < DD; d += 256) {
    float dd = S.tl[d] - mu;
    vsum += dd * dd;
  }
#pragma unroll
  for (int m = 1; m < 64; m <<= 1) vsum += __shfl_xor(vsum, m, 64);
  if (lane == 0) S.red2[wv] = vsum;
  __syncthreads();
  float var = (S.red2[0] + S.red2[1] + S.red2[2] + S.red2[3]) * (1.0f / (float)DD);
  float inv = rsqrtf(var + 1e-5f);
  float pi = (float)(*pidx);
  for (int d = tid; d < DD; d += 256) {
    float tn = (S.tl[d] - mu) * inv * fg[d] + fb[d];
    float hv = (hf[b * DD + d] * pi + tn) / (pi + 1.0f);
    S.hl[d] = hv;
    out[BB * NCi + b * DD + d] = hv;
  }
  __syncthreads();
  for (int n = wv; n < NCi; n += 4) {
    float s = 0.f;
    for (int d = lane; d < DD; d += 64) s += S.hl[d] * fcw[(size_t)n * DD + d];
#pragma unroll
    for (int m = 1; m < 64; m <<= 1) s += __shfl_xor(s, m, 64);
    if (lane == 0) out[b * NCi + n] = s + fcb[n];
  }
}

// ---------------------------------------------------------------------------
// The persistent mega-kernel: all 46 former dispatches, 45 grid barriers.
// ---------------------------------------------------------------------------
__global__ __launch_bounds__(256, 2) void mega(P p) {
  __shared__ char smem[36864] __attribute__((aligned(16)));
  int bid = blockIdx.x, tid = threadIdx.x;
  unsigned* flags = p.barr;
  unsigned* go = p.barr + GRID;
  unsigned ph = 0;

  // ---- CNN frontend ----
  st_patch(p, bid, tid);
  gridbar(flags, go, ++ph, bid, tid);
  st_conv<10, 6>(p.cin0, p.cw4, p.part, bid, tid, smem);
  gridbar(flags, go, ++ph, bid, tid);
  st_bnrelu<6, 1, 0, 10>(p.part, p.cb4, p.bg, p.bnb, p.brm, p.brv, p.cin1,
                         p.cst + (size_t)1 * BB * DD * 4, p.pos, p.pidx, bid, tid);
  gridbar(flags, go, ++ph, bid, tid);
  st_conv<10, 6>(p.cin1, p.cw4 + (size_t)1 * DD * DD * 5, p.part, bid, tid, smem);
  gridbar(flags, go, ++ph, bid, tid);
  st_bnrelu<6, 3, 0, 6>(p.part, p.cb4 + DD, p.bg + DD, p.bnb + DD, p.brm + DD, p.brv + DD,
                        p.cin2, p.cst + (size_t)2 * BB * DD * 4, p.pos, p.pidx, bid, tid);
  gridbar(flags, go, ++ph, bid, tid);
  st_conv<6, 2>(p.cin2, p.cw4 + (size_t)2 * DD * DD * 5, p.part, bid, tid, smem);
  gridbar(flags, go, ++ph, bid, tid);
  st_bnrelu<2, 1, 0, 6>(p.part, p.cb4 + 2 * DD, p.bg + 2 * DD, p.bnb + 2 * DD, p.brm + 2 * DD,
                        p.brv + 2 * DD, p.cin3, p.cst + (size_t)3 * BB * DD * 4, p.pos, p.pidx,
                        bid, tid);
  gridbar(flags, go, ++ph, bid, tid);
  st_conv<6, 2>(p.cin3, p.cw4 + (size_t)3 * DD * DD * 5, p.part, bid, tid, smem);
  gridbar(flags, go, ++ph, bid, tid);
  st_bnrelu<2, 2, 1, 0>(p.part, p.cb4 + 3 * DD, p.bg + 3 * DD, p.bnb + 3 * DD, p.brm + 3 * DD,
                        p.brv + 3 * DD, p.t0, nullptr, p.pos, p.pidx, bid, tid);
  gridbar(flags, go, ++ph, bid, tid);

  // ---- 12 sequential Mamba layers (lazy residual via dp partials) ----
  for (int L = 0; L < NLAYER; L++) {
    const float* rd = (L == 0 || (L & 1)) ? p.t0 : p.t1;
    float* wr = (L == 0) ? p.t1 : ((L & 1) ? p.t1 : p.t0);
    st_inproj(p.ipw + (size_t)L * RIN * DD, rd, p.dp, (L > 0) ? 1 : 0, wr, p.zx, p.sq, bid, tid,
              smem);
    gridbar(flags, go, ++ph, bid, tid);
    st_ssm(p, L, bid, tid, smem);
    gridbar(flags, go, ++ph, bid, tid);
    st_outproj(p.opw + (size_t)L * DD * DIi, p.yb, p.zx, p.sq, p.nw + (size_t)L * DIi, p.dp, bid,
               tid, smem);
    gridbar(flags, go, ++ph, bid, tid);
  }

  // ---- final layernorm + history + logits (tok after layer 11 = t1 + dp) ----
  st_final(p.t1, p.dp, p.hf, p.fg, p.fb, p.fcw, p.fcb, p.pidx, p.out, bid, tid, smem);
}

// ---------------------------------------------------------------------------
extern "C" void kernel_launch(void* const* d_in, const int* in_sizes, int n_in,
                              void* d_out, int out_size, void* d_ws, size_t ws_size,
                              hipStream_t stream) {
  (void)in_sizes; (void)n_in; (void)out_size; (void)ws_size;
  float* ws = (float*)d_ws;

  P p;
  p.x    = (const float*)d_in[0];
  p.hf   = (const float*)d_in[1];
  p.pw   = (const float*)d_in[2];
  p.pb   = (const float*)d_in[3];
  p.cw4  = (const float*)d_in[4];
  p.cb4  = (const float*)d_in[5];
  p.bg   = (const float*)d_in[6];
  p.bnb  = (const float*)d_in[7];
  p.brm  = (const float*)d_in[8];
  p.brv  = (const float*)d_in[9];
  p.cst  = (const float*)d_in[10];
  p.pos  = (const float*)d_in[11];
  p.ipw  = (const float*)d_in[12];
  p.cw   = (const float*)d_in[13];
  p.cb1  = (const float*)d_in[14];
  p.alog = (const float*)d_in[15];
  p.dtb  = (const float*)d_in[16];
  p.dpar = (const float*)d_in[17];
  p.nw   = (const float*)d_in[18];
  p.opw  = (const float*)d_in[19];
  p.mcs  = (const float*)d_in[20];
  p.ssm  = (const float*)d_in[21];
  p.fg   = (const float*)d_in[22];
  p.fb   = (const float*)d_in[23];
  p.fcw  = (const float*)d_in[24];
  p.fcb  = (const float*)d_in[25];
  p.pidx = (const int*)d_in[26];
  p.out  = (float*)d_out;

  p.cin0 = ws;                   // 32*768*10 = 245760
  p.cin1 = p.cin0 + 245760;      // 245760
  p.cin2 = p.cin1 + 245760;      // 32*768*6 = 147456
  p.cin3 = p.cin2 + 147456;      // 147456
  p.part = p.cin3 + 147456;      // 16*768*192 = 2359296
  p.t0   = p.part + 2359296;     // 24576
  p.t1   = p.t0 + 24576;         // 24576
  p.zx   = p.t1 + 24576;         // 4*32*3336 = 427008
  p.yb   = p.zx + 427008;        // 49152
  p.sq   = p.yb + 49152;         // 32
  p.dp   = p.sq + 32;            // 4*32*768 = 98304
  p.barr = (unsigned*)(p.dp + 98304);  // GRID flags + go

  // ws is poisoned between iterations -> barrier state must be re-zeroed
  // inside the captured graph, before the persistent kernel runs.
  hipMemsetAsync((void*)p.barr, 0, (GRID + 8) * sizeof(unsigned), stream);
  mega<<<dim3(GRID), dim3(256), 0, stream>>>(p);
}